// Round 5
// baseline (279.930 us; speedup 1.0000x reference)
//
#include <hip/hip_runtime.h>
#include <hip/hip_bf16.h>
#include <stdint.h>

// Problem constants (from reference)
#define N_TOKENS   4096
#define IN_FEAT    1024
#define OUT_FEAT   2048
#define NUM_EXPERT 16

#define BM 128                // row-padding quantum (routing)
#define BK 32                 // K-slice per MFMA step
#define BNW 64                // per-block n-window (W panel rows in LDS)
#define MAX_ROWS  6144        // padded sorted rows upper bound (<=6016)

typedef __bf16 bf16x8 __attribute__((ext_vector_type(8)));
typedef float  f32x4  __attribute__((ext_vector_type(4)));
typedef unsigned short us8 __attribute__((ext_vector_type(8)));  // 16B

__device__ __forceinline__ unsigned short f32_to_bf16_rne(float f) {
  union { float f; uint32_t u; } v; v.f = f;
  uint32_t u = v.u;
  u += 0x7fffu + ((u >> 16) & 1u);   // round-nearest-even
  return (unsigned short)(u >> 16);
}

// ---------------------------------------------------------------------------
// Kernel 1: routing setup (single block). Histogram, padded prefix, scatter.
// pstart[17]: padded segment starts, pstart[16] = total padded rows.
// ---------------------------------------------------------------------------
__global__ void k_setup(const int* __restrict__ gate,
                        int* __restrict__ pstart,     // [17]
                        int* __restrict__ row_token)  // [MAX_ROWS], -1 = pad
{
  __shared__ int cnt[NUM_EXPERT];
  __shared__ int cur[NUM_EXPERT];
  __shared__ int ps[NUM_EXPERT];
  const int tid = threadIdx.x;
  if (tid < NUM_EXPERT) { cnt[tid] = 0; cur[tid] = 0; }
  __syncthreads();
  for (int b = tid; b < N_TOKENS; b += 256) atomicAdd(&cnt[gate[b]], 1);
  for (int r = tid; r < MAX_ROWS; r += 256) row_token[r] = -1;
  __syncthreads();
  if (tid == 0) {
    int p = 0;
    for (int e = 0; e < NUM_EXPERT; ++e) {
      ps[e] = p; pstart[e] = p;
      p += ((cnt[e] + BM - 1) / BM) * BM;
    }
    pstart[NUM_EXPERT] = p;
  }
  __syncthreads();
  for (int b = tid; b < N_TOKENS; b += 256) {
    int e = gate[b];
    int pos = atomicAdd(&cur[e], 1);
    row_token[ps[e] + pos] = b;
  }
}

// ---------------------------------------------------------------------------
// Kernel 2: gather x into sorted padded order + cast to bf16; pads -> zeros.
// ---------------------------------------------------------------------------
__global__ void k_gather_x(const float4* __restrict__ x,
                           const int* __restrict__ row_token,
                           us8* __restrict__ xs) {
  const int r = blockIdx.x * 2 + (threadIdx.x >> 7);
  const int c = threadIdx.x & 127;
  const int tok = row_token[r];
  us8 o;
  if (tok >= 0) {
    float4 a = x[tok * 256 + c * 2];
    float4 b = x[tok * 256 + c * 2 + 1];
    o[0] = f32_to_bf16_rne(a.x); o[1] = f32_to_bf16_rne(a.y);
    o[2] = f32_to_bf16_rne(a.z); o[3] = f32_to_bf16_rne(a.w);
    o[4] = f32_to_bf16_rne(b.x); o[5] = f32_to_bf16_rne(b.y);
    o[6] = f32_to_bf16_rne(b.z); o[7] = f32_to_bf16_rne(b.w);
  } else {
    o = (us8)0;
  }
  xs[r * 128 + c] = o;
}

// ---------------------------------------------------------------------------
// Kernel 3: grouped GEMM, W-PANEL-RESIDENT / BARRIER-FREE K-LOOP.
// Grid = 16 experts x 32 n-windows = 512 blocks, 512 threads (8 waves),
// 1 block/CU resident (128 KB LDS), 2 sequential blocks per CU.
//
// Phase 1 (once): stage W[e][nwin:nwin+64][:] fp32 -> bf16 into LDS
//   (convert-ONCE; R4 converted each element 8x redundantly). Chunk-swizzled:
//   16B chunk c of row n stored at c ^ (n&7)  -> ds_read_b128 in the K-loop
//   hits each bank exactly the unavoidable 8x (conflict-free).
// __syncthreads()  -- the ONLY barrier in the kernel.
// Phase 2: waves INDEPENDENTLY process 64-row chunks of the expert segment
//   (ch = wid, wid+8, ...). Per K-step: 4 A global->VGPR loads (16B frags
//   from the L2-resident xs panel; expert-e blocks share id%8=e%8 -> XCD
//   locality), 4 ds_read_b128 B frags (bf16), 16 MFMA. No barriers, no
//   inline-asm waits: waves drift apart and the compiler software-pipelines
//   freely -- this removes the 2-barriers-per-K-step lockstep that pinned
//   R0/R2/R4 at ~6750 cy/step (~4000 cy of it stall) regardless of staging
//   strategy or byte volume.
// Row waste: chunks cover exactly seg_len (multiple of 128) rows; pad rows
// have xs=0 (harmless) and row_token=-1 (store-guarded).
// ---------------------------------------------------------------------------
__global__ void __launch_bounds__(512, 2)
k_gemm(const unsigned short* __restrict__ xs,   // [MAX_ROWS][IN_FEAT] bf16
       const float* __restrict__ w,             // [E][OUT_FEAT][IN_FEAT] fp32
       const int* __restrict__ pstart,          // [17]
       const int* __restrict__ row_token,
       float* __restrict__ out) {
  __shared__ us8 Bs[BNW * 128];   // 64 rows x 128 chunks x 16B = 128 KB bf16

  const int e    = blockIdx.x;                 // id%8 = e%8 -> XCD grouping
  const int nwin = blockIdx.y * BNW;
  const int seg0 = pstart[e];
  const int seg_len = pstart[e + 1] - seg0;    // padded (multiple of 128)
  if (seg_len <= 0) return;                    // block-uniform

  const int tid  = threadIdx.x;
  const int wid  = tid >> 6;        // 0..7
  const int lane = tid & 63;
  const int lr   = lane & 15;
  const int quad = lane >> 4;

  // ---- Phase 1: stage W panel, fp32 -> bf16, convert-once, swizzled ----
  {
    const int n  = tid >> 3;          // 0..63  panel row (W output col)
    const int c8 = tid & 7;           // chunk sub-index
    const float* wp = w + (size_t)e * OUT_FEAT * IN_FEAT
                        + (size_t)(nwin + n) * IN_FEAT;
#pragma unroll
    for (int p = 0; p < 16; ++p) {
      const int c = p * 8 + c8;                     // 16B chunk 0..127
      const float4 a = *(const float4*)(wp + c * 8);
      const float4 b = *(const float4*)(wp + c * 8 + 4);
      us8 o;
      o[0] = f32_to_bf16_rne(a.x); o[1] = f32_to_bf16_rne(a.y);
      o[2] = f32_to_bf16_rne(a.z); o[3] = f32_to_bf16_rne(a.w);
      o[4] = f32_to_bf16_rne(b.x); o[5] = f32_to_bf16_rne(b.y);
      o[6] = f32_to_bf16_rne(b.z); o[7] = f32_to_bf16_rne(b.w);
      Bs[n * 128 + (c ^ (n & 7))] = o;
    }
  }
  __syncthreads();   // the only barrier: panel now read-only

  // ---- Phase 2: barrier-free per-wave GEMM over 64-row chunks ----
  const int nch = seg_len >> 6;    // 64-row chunks (seg_len % 128 == 0)

  for (int ch = wid; ch < nch; ch += 8) {
    const int r0 = ch * 64;
    // A frag base: row = seg0 + r0 + mi*16 + lr, cols [k0 + quad*8, +8)
    const unsigned short* ap =
        xs + (size_t)(seg0 + r0 + lr) * IN_FEAT + quad * 8;

    f32x4 acc[4][4];
    const f32x4 z = {0.f, 0.f, 0.f, 0.f};
#pragma unroll
    for (int i = 0; i < 4; ++i)
#pragma unroll
      for (int j = 0; j < 4; ++j) acc[i][j] = z;

#pragma unroll 4
    for (int k0 = 0; k0 < IN_FEAT; k0 += BK) {
      bf16x8 af[4], bf[4];
#pragma unroll
      for (int mi = 0; mi < 4; ++mi)
        af[mi] = *(const bf16x8*)(ap + (size_t)mi * 16 * IN_FEAT + k0);
#pragma unroll
      for (int ni = 0; ni < 4; ++ni) {
        const int n = ni * 16 + lr;
        bf[ni] = *(const bf16x8*)&Bs[n * 128 + ((k0 / 8 + quad) ^ (n & 7))];
      }
#pragma unroll
      for (int mi = 0; mi < 4; ++mi)
#pragma unroll
        for (int ni = 0; ni < 4; ++ni)
          acc[mi][ni] = __builtin_amdgcn_mfma_f32_16x16x32_bf16(
              af[mi], bf[ni], acc[mi][ni], 0, 0, 0);
    }

    // Epilogue: C/D layout col=lane&15, row=quad*4+reg (verified m89/m91).
    // row_token reads are 16-lane-uniform -> broadcast, L1/L2-hot.
#pragma unroll
    for (int mi = 0; mi < 4; ++mi) {
      const int mb = r0 + mi * 16 + quad * 4;
      const int t0 = row_token[seg0 + mb + 0];
      const int t1 = row_token[seg0 + mb + 1];
      const int t2 = row_token[seg0 + mb + 2];
      const int t3 = row_token[seg0 + mb + 3];
#pragma unroll
      for (int ni = 0; ni < 4; ++ni) {
        const int n = nwin + ni * 16 + lr;
        f32x4 c = acc[mi][ni];
        if (t0 >= 0) out[(size_t)t0 * OUT_FEAT + n] = c[0];
        if (t1 >= 0) out[(size_t)t1 * OUT_FEAT + n] = c[1];
        if (t2 >= 0) out[(size_t)t2 * OUT_FEAT + n] = c[2];
        if (t3 >= 0) out[(size_t)t3 * OUT_FEAT + n] = c[3];
      }
    }
  }
}

// ---------------------------------------------------------------------------
extern "C" void kernel_launch(void* const* d_in, const int* in_sizes, int n_in,
                              void* d_out, int out_size, void* d_ws, size_t ws_size,
                              hipStream_t stream) {
  const float* x    = (const float*)d_in[0];
  const int*   gate = (const int*)d_in[1];
  const float* w    = (const float*)d_in[2];
  float* out = (float*)d_out;

  // workspace layout (~13 MB)
  char* ws = (char*)d_ws;
  unsigned short* xs = (unsigned short*)ws;                        // 12 MB
  int* row_token = (int*)(ws + 12582912);                          // 24 KB
  int* pstart = row_token + MAX_ROWS;                              // 17 ints

  k_setup<<<1, 256, 0, stream>>>(gate, pstart, row_token);
  k_gather_x<<<MAX_ROWS / 2, 256, 0, stream>>>((const float4*)x, row_token,
                                               (us8*)xs);
  dim3 g(NUM_EXPERT, OUT_FEAT / BNW);   // (16, 32) = 512 blocks
  k_gemm<<<g, 512, 0, stream>>>(xs, w, pstart, row_token, out);
}

// Round 6
// 269.759 us; speedup vs baseline: 1.0377x; 1.0377x over previous
//
#include <hip/hip_runtime.h>
#include <hip/hip_bf16.h>
#include <stdint.h>

// Problem constants (from reference)
#define N_TOKENS   4096
#define IN_FEAT    1024
#define OUT_FEAT   2048
#define NUM_EXPERT 16

#define BK 32                 // K-slice per pipeline step
#define NT (IN_FEAT / BK)     // 32 K-steps
#define BNW 128               // per-block n-window (weight panel width)
#define GROWS 512             // rows per group (8 waves x 64 rows)

typedef __bf16 bf16x8 __attribute__((ext_vector_type(8)));
typedef float  f32x4  __attribute__((ext_vector_type(4)));

// async global->LDS, 16B per lane. LDS dest is wave-uniform base + lane*16;
// source address is PER-LANE (so we pre-swizzle the source).
__device__ __forceinline__ void async_copy16(const void* g, void* l) {
  __builtin_amdgcn_global_load_lds(
      (const __attribute__((address_space(1))) unsigned int*)g,
      (__attribute__((address_space(3))) unsigned int*)l, 16, 0, 0);
}

// ---------------------------------------------------------------------------
// SINGLE FUSED KERNEL: routing + grouped GEMM (W-streaming, x-direct).
//
// Motivation (R5 post-mortem): total - k_gemm == ~172 us CONSTANT across all
// five rounds -- k_setup + k_gather_x + inter-kernel gaps were ~2/3 of the
// measured time. This kernel eliminates both helper kernels and the
// workspace: each block routes for itself.
//
// Grid = 16 experts x 16 n-windows = 256 blocks, 512 threads (8 waves).
// id%8 = e%8 -> all blocks of expert e on one XCD (x rows L2-resident).
//
// Per block:
//  0. Issue B-DMA for k=0 (overlaps routing scan).
//  1. Routing: scan gate[4096] (8 iters/thread), matched tokens -> LDS list
//     via atomicAdd. Order irrelevant (each out element written once).
//  2. GEMM (R4-proven core, measured 90 us): W[e][nwin:+128][:] streamed
//     ONCE via double-buffered global_load_lds (pre-swizzled source, counted
//     vmcnt -- never 0 in the main loop). A fragments loaded per-lane
//     token-indexed direct from x (f32), converted f32->bf16 RNE in regs
//     (bit-identical to the old gather+xs path). fp32->bf16 B convert in
//     regs between ds_read and MFMA.
//  B LDS layout: slot(r,c) = r*8 + (c ^ (r&7)), c = 16B chunk 0..7.
//  Out-of-count slots: A clamped to toks[0] (garbage acc), stores guarded.
// ---------------------------------------------------------------------------
__global__ void __launch_bounds__(512, 2)
k_moe(const float* __restrict__ x,              // [N_TOKENS][IN_FEAT] fp32
      const int* __restrict__ gate,             // [N_TOKENS]
      const float* __restrict__ w,              // [E][OUT_FEAT][IN_FEAT] fp32
      float* __restrict__ out) {                // [N_TOKENS][OUT_FEAT]
  __shared__ f32x4 Bs[2][1024];                 // 2 x 16 KB k-slice dbuf
  __shared__ unsigned short toks[N_TOKENS];     // 8 KB token list
  __shared__ int cnt_s;

  const int e    = blockIdx.x;                  // id%8 = e%8 -> XCD grouping
  const int nwin = blockIdx.y * BNW;

  const int tid  = threadIdx.x;
  const int wid  = tid >> 6;        // 0..7 -> wave m-slice (64 rows)
  const int lane = tid & 63;
  const int lr   = lane & 15;
  const int quad = lane >> 4;

  // B staging source: thread covers B-row rB (and rB+64), chunk pre-swizzled
  // so the linear-dest DMA realizes slot(r,c) = r*8 + (c ^ (r&7)).
  const int rB = tid >> 3;                        // 0..63
  const int cB = (tid & 7) ^ (rB & 7);            // 16B chunk within 128B row
  const float* bgp = w + (size_t)e * OUT_FEAT * IN_FEAT
                       + (size_t)(nwin + rB) * IN_FEAT + cB * 4;

  auto stageB = [&](int t, int b) {
    const int k0 = t * BK;
    async_copy16(bgp + k0,                Bs[b] +       wid * 64);  // rows 0..63
    async_copy16(bgp + 64 * IN_FEAT + k0, Bs[b] + 512 + wid * 64);  // rows 64..127
  };

  // ---- 0+1: first B-DMA, then routing scan (scan hides DMA latency) ----
  stageB(0, 0);

  if (tid == 0) cnt_s = 0;
  __syncthreads();
  for (int b = tid; b < N_TOKENS; b += 512) {
    if (gate[b] == e) {
      int p = atomicAdd(&cnt_s, 1);
      toks[p] = (unsigned short)b;
    }
  }
  __syncthreads();
  const int cnt = cnt_s;
  if (cnt == 0) {             // uniform exit; drain DMA so a successor
    asm volatile("s_waitcnt vmcnt(0)" ::: "memory");  // block's LDS is safe
    return;
  }

  const int nG = (cnt + GROWS - 1) / GROWS;     // 1 for all realistic counts

  for (int g = 0; g < nG; ++g) {
    if (g > 0) stageB(0, 0);                    // restream panel (rare path)

    // Per-mi A base pointers (k-invariant; clamp out-of-count slots).
    const float* ap[4];
#pragma unroll
    for (int mi = 0; mi < 4; ++mi) {
      const int s = g * GROWS + wid * 64 + mi * 16 + lr;
      const int tk = (s < cnt) ? (int)toks[s] : (int)toks[0];
      ap[mi] = x + (size_t)tk * IN_FEAT + quad * 8;
    }

    // Raw f32 A fragments: 4 frags x 32B = 8 x float4 (named double-buffer).
    auto loadAraw = [&](int t, f32x4* dst) {
#pragma unroll
      for (int mi = 0; mi < 4; ++mi) {
        dst[mi * 2]     = *(const f32x4*)(ap[mi] + t * BK);
        dst[mi * 2 + 1] = *(const f32x4*)(ap[mi] + t * BK + 4);
      }
    };

    f32x4 acc[4][8];
    const f32x4 z = {0.f, 0.f, 0.f, 0.f};
#pragma unroll
    for (int i = 0; i < 4; ++i)
#pragma unroll
      for (int j = 0; j < 8; ++j) acc[i][j] = z;

    f32x4 rawA[8], rawB[8];    // static-indexed double buffer (rule #20)
    loadAraw(0, rawA);         // prologue: 2 DMA + 8 A loads = 10 in flight

    auto step = [&](int t, const f32x4* rawc, f32x4* rawn) {
      const int buf = t & 1;
      if (t + 1 < NT) {
        stageB(t + 1, buf ^ 1);      // 2 DMA (newest)
        loadAraw(t + 1, rawn);       // 8 A loads (newest)
        // all but the 10 just-issued retired -> stage-t B (and step-t A)
        // landed. Never drains to 0 in the main loop.
        asm volatile("s_waitcnt vmcnt(10)" ::: "memory");
      } else {
        asm volatile("s_waitcnt vmcnt(0)" ::: "memory");
      }
      __builtin_amdgcn_s_barrier();   // stage-t B visible to all waves
      asm volatile("" ::: "memory");

      bf16x8 af[4];
#pragma unroll
      for (int mi = 0; mi < 4; ++mi) {
        const f32x4 a0 = rawc[mi * 2];
        const f32x4 a1 = rawc[mi * 2 + 1];
        bf16x8 a;
        a[0] = (__bf16)a0[0]; a[1] = (__bf16)a0[1];
        a[2] = (__bf16)a0[2]; a[3] = (__bf16)a0[3];
        a[4] = (__bf16)a1[0]; a[5] = (__bf16)a1[1];
        a[6] = (__bf16)a1[2]; a[7] = (__bf16)a1[3];
        af[mi] = a;
      }

      bf16x8 bf[8];
#pragma unroll
      for (int ni = 0; ni < 8; ++ni) {
        const int n = ni * 16 + lr;
        f32x4 c0 = Bs[buf][n * 8 + ((2 * quad)     ^ (n & 7))];
        f32x4 c1 = Bs[buf][n * 8 + ((2 * quad + 1) ^ (n & 7))];
        bf16x8 b;
        b[0] = (__bf16)c0[0]; b[1] = (__bf16)c0[1];
        b[2] = (__bf16)c0[2]; b[3] = (__bf16)c0[3];
        b[4] = (__bf16)c1[0]; b[5] = (__bf16)c1[1];
        b[6] = (__bf16)c1[2]; b[7] = (__bf16)c1[3];
        bf[ni] = b;
      }
#pragma unroll
      for (int mi = 0; mi < 4; ++mi)
#pragma unroll
        for (int ni = 0; ni < 8; ++ni)
          acc[mi][ni] = __builtin_amdgcn_mfma_f32_16x16x32_bf16(
              af[mi], bf[ni], acc[mi][ni], 0, 0, 0);

      asm volatile("" ::: "memory");
      __builtin_amdgcn_s_barrier();   // reads of Bs[buf] done before overwrite
    };

    for (int t = 0; t < NT; t += 2) {   // NT even; keeps raw A regs named
      step(t,     rawA, rawB);
      step(t + 1, rawB, rawA);
    }

    // Epilogue: C/D layout col=lane&15, row=quad*4+reg (verified m89/m91).
#pragma unroll
    for (int mi = 0; mi < 4; ++mi) {
      const int mb = g * GROWS + wid * 64 + mi * 16 + quad * 4;
#pragma unroll
      for (int ni = 0; ni < 8; ++ni) {
        const int n = nwin + ni * 16 + lr;
        f32x4 c = acc[mi][ni];
        if (mb + 0 < cnt) out[(size_t)toks[mb + 0] * OUT_FEAT + n] = c[0];
        if (mb + 1 < cnt) out[(size_t)toks[mb + 1] * OUT_FEAT + n] = c[1];
        if (mb + 2 < cnt) out[(size_t)toks[mb + 2] * OUT_FEAT + n] = c[2];
        if (mb + 3 < cnt) out[(size_t)toks[mb + 3] * OUT_FEAT + n] = c[3];
      }
    }
  }
}

// ---------------------------------------------------------------------------
extern "C" void kernel_launch(void* const* d_in, const int* in_sizes, int n_in,
                              void* d_out, int out_size, void* d_ws, size_t ws_size,
                              hipStream_t stream) {
  const float* x    = (const float*)d_in[0];
  const int*   gate = (const int*)d_in[1];
  const float* w    = (const float*)d_in[2];
  float* out = (float*)d_out;

  // ONE launch: routing fused into the GEMM; no workspace, no helper kernels.
  dim3 g(NUM_EXPERT, OUT_FEAT / BNW);   // (16, 16) = 256 blocks
  k_moe<<<g, 512, 0, stream>>>(x, gate, w, out);
}

// Round 7
// 264.864 us; speedup vs baseline: 1.0569x; 1.0185x over previous
//
#include <hip/hip_runtime.h>
#include <hip/hip_bf16.h>
#include <stdint.h>

// Problem constants (from reference)
#define N_TOKENS   4096
#define IN_FEAT    1024
#define OUT_FEAT   2048
#define NUM_EXPERT 16

// GEMM tiling: 256x128 tile, BK=32, 512 threads (8 waves = 4m x 2n).
#define BM 256
#define BN 128
#define BK 32
#define NT (IN_FEAT / BK)     // 32 K-steps
#define MAX_TILES 32          // sum_e ceil(cnt_e/256) <= 32
#define MAX_ROWS  8192        // padded rows <= 32*256

typedef __bf16 bf16x8 __attribute__((ext_vector_type(8)));
typedef float  f32x4  __attribute__((ext_vector_type(4)));
typedef unsigned short us8 __attribute__((ext_vector_type(8)));  // 16B

__device__ __forceinline__ unsigned short f32_to_bf16_rne(float f) {
  union { float f; uint32_t u; } v; v.f = f;
  uint32_t u = v.u;
  u += 0x7fffu + ((u >> 16) & 1u);   // round-nearest-even
  return (unsigned short)(u >> 16);
}

// async global->LDS, 16B per lane. LDS dest is wave-uniform base + lane*16;
// source address is PER-LANE (so scattered/pre-swizzled sources are fine).
__device__ __forceinline__ void async_copy16(const void* g, void* l) {
  __builtin_amdgcn_global_load_lds(
      (const __attribute__((address_space(1))) unsigned int*)g,
      (__attribute__((address_space(3))) unsigned int*)l, 16, 0, 0);
}

// ---------------------------------------------------------------------------
// Kernel 1: routing setup (single block). Histogram, padded prefix, scatter.
// Padding quantum = BM = 256.
// ---------------------------------------------------------------------------
__global__ void k_setup(const int* __restrict__ gate,
                        int* __restrict__ pstart,     // [16] padded seg start
                        int* __restrict__ tile_e,     // [MAX_TILES]
                        int* __restrict__ tile_m,     // [MAX_TILES]
                        int* __restrict__ row_token)  // [MAX_ROWS], -1 = pad
{
  __shared__ int cnt[NUM_EXPERT];
  __shared__ int cur[NUM_EXPERT];
  __shared__ int ps[NUM_EXPERT];
  const int tid = threadIdx.x;
  if (tid < NUM_EXPERT) { cnt[tid] = 0; cur[tid] = 0; }
  __syncthreads();
  for (int b = tid; b < N_TOKENS; b += 256) atomicAdd(&cnt[gate[b]], 1);
  for (int r = tid; r < MAX_ROWS; r += 256) row_token[r] = -1;
  __syncthreads();
  if (tid == 0) {
    int p = 0, tot = 0;
    for (int e = 0; e < NUM_EXPERT; ++e) {
      ps[e] = p; pstart[e] = p;
      int nt = (cnt[e] + BM - 1) / BM;
      for (int t = 0; t < nt; ++t) { tile_e[tot] = e; tile_m[tot] = t; ++tot; }
      p += nt * BM;
    }
    for (int s = tot; s < MAX_TILES; ++s) { tile_e[s] = -1; tile_m[s] = 0; }
  }
  __syncthreads();
  for (int b = tid; b < N_TOKENS; b += 256) {
    int e = gate[b];
    int pos = atomicAdd(&cur[e], 1);
    row_token[ps[e] + pos] = b;
  }
}

// ---------------------------------------------------------------------------
// Kernel 2: DENSE token-order cast x (f32) -> xs (bf16). No gather/sort:
// the GEMM's A-DMA sources are row_token-indexed per-lane instead.
// ---------------------------------------------------------------------------
__global__ void k_cast(const float4* __restrict__ x, us8* __restrict__ xs) {
  const int i = blockIdx.x * 256 + threadIdx.x;   // one us8 (8 elems) each
  float4 a = x[i * 2];
  float4 b = x[i * 2 + 1];
  us8 o;
  o[0] = f32_to_bf16_rne(a.x); o[1] = f32_to_bf16_rne(a.y);
  o[2] = f32_to_bf16_rne(a.z); o[3] = f32_to_bf16_rne(a.w);
  o[4] = f32_to_bf16_rne(b.x); o[5] = f32_to_bf16_rne(b.y);
  o[6] = f32_to_bf16_rne(b.z); o[7] = f32_to_bf16_rne(b.w);
  xs[i] = o;
}

// ---------------------------------------------------------------------------
// Kernel 3: grouped GEMM, 256x128 tile (byte-cut: B staged 384->~145 MB,
// total ~290 MB at the measured 6.5 TB/s fabric rate). All staging/swizzle
// formulas are R0-proven, verbatim:
//   A (bf16): slot(r,c) = r*4 + (c ^ ((r>>1)&3)), c = 16B chunk 0..3.
//   B (fp32): slot(r,c) = r*8 + (c ^ (r&7)),      c = 16B chunk 0..7.
// 8 waves (4m x 2n), each wave 4x4 frags of mfma_f32_16x16x32_bf16.
// Double-buffered, counted vmcnt (never 0 in the main loop), raw barriers.
// A-DMA sources are per-lane row_token-indexed (pads -> row 0, stores
// guarded); fp32->bf16 B convert in regs between ds_read and MFMA.
// ---------------------------------------------------------------------------
__global__ void __launch_bounds__(512, 4)
k_gemm(const unsigned short* __restrict__ xs,   // [N_TOKENS][IN_FEAT] bf16
       const float* __restrict__ w,             // [E][OUT_FEAT][IN_FEAT] fp32
       const int* __restrict__ pstart,
       const int* __restrict__ tile_e,
       const int* __restrict__ tile_m,
       const int* __restrict__ row_token,
       float* __restrict__ out) {
  __shared__ us8   As[2][1024];    // 2 x 16 KB  (256 rows x 32 k bf16)
  __shared__ f32x4 Bs[2][1024];    // 2 x 16 KB  (128 rows x 32 k fp32)
  __shared__ int rowtok_s[BM];     // 1 KB

  const int slot = blockIdx.y;
  const int e = tile_e[slot];
  if (e < 0) return;
  const int seg0 = pstart[e] + tile_m[slot] * BM;
  const int n0 = blockIdx.x * BN;

  const int tid  = threadIdx.x;
  const int wid  = tid >> 6;        // 0..7
  const int lane = tid & 63;
  const int lr   = lane & 15;
  const int quad = lane >> 4;
  const int wm   = (wid >> 1) * 64;   // wave m-offset (4 m-waves)
  const int wn   = (wid & 1) * 64;    // wave n-offset (2 n-waves)

  if (tid < BM) rowtok_s[tid] = row_token[seg0 + tid];

  // A-DMA sources: 4 lanes per row; rows are row_token-indexed into the
  // dense xs (pads clamp to token 0; their outputs are store-guarded).
  const int cA = (tid & 3) ^ ((tid >> 3) & 3);   // A chunk (16B), R0 formula
  const int rt0 = row_token[seg0 + (tid >> 2)];
  const int rt1 = row_token[seg0 + 128 + (tid >> 2)];
  const unsigned short* agp0 =
      xs + (size_t)(rt0 < 0 ? 0 : rt0) * IN_FEAT + cA * 8;
  const unsigned short* agp1 =
      xs + (size_t)(rt1 < 0 ? 0 : rt1) * IN_FEAT + cA * 8;

  // B staging source (swizzled chunk is round-invariant), R0 formula.
  const int cB = (tid & 7) ^ ((tid >> 3) & 7);
  const float* bgp = w + (size_t)e * OUT_FEAT * IN_FEAT
                       + (size_t)(n0 + (tid >> 3)) * IN_FEAT + cB * 4;

  f32x4 acc[4][4];
  const f32x4 z = {0.f, 0.f, 0.f, 0.f};
#pragma unroll
  for (int i = 0; i < 4; ++i)
#pragma unroll
    for (int j = 0; j < 4; ++j) acc[i][j] = z;

  // 4 async DMA per thread per stage (A rows 0-127, 128-255; B rows 0-63,
  // 64-127). Dest slots are linear in tid per round (R0-verified mapping).
  auto stage = [&](int t, int b) {
    const int k0 = t * BK;
    async_copy16(agp0 + k0,                As[b] +       wid * 64);
    async_copy16(agp1 + k0,                As[b] + 512 + wid * 64);
    async_copy16(bgp + k0,                 Bs[b] +       wid * 64);
    async_copy16(bgp + 64 * IN_FEAT + k0,  Bs[b] + 512 + wid * 64);
  };

  stage(0, 0);   // prologue: 4 DMA in flight

  // Publish rowtok_s (raw s_barrier does not drain lgkmcnt).
  asm volatile("s_waitcnt lgkmcnt(0)" ::: "memory");
  __builtin_amdgcn_s_barrier();

  for (int t = 0; t < NT; ++t) {
    const int buf = t & 1;
    if (t + 1 < NT) {
      stage(t + 1, buf ^ 1);  // 8 in flight: 4 old (stage t) + 4 new
      // wait until only the 4 just-issued remain -> stage t landed.
      asm volatile("s_waitcnt vmcnt(4)" ::: "memory");
    } else {
      asm volatile("s_waitcnt vmcnt(0)" ::: "memory");
    }
    __builtin_amdgcn_s_barrier();   // stage-t visible to all waves
    asm volatile("" ::: "memory");

    bf16x8 af[4], bf[4];
#pragma unroll
    for (int mi = 0; mi < 4; ++mi) {
      const int n = wm + mi * 16 + lr;
      af[mi] = *(const bf16x8*)&As[buf][n * 4 + (quad ^ ((n >> 1) & 3))];
    }
#pragma unroll
    for (int ni = 0; ni < 4; ++ni) {
      const int n = wn + ni * 16 + lr;
      f32x4 c0 = Bs[buf][n * 8 + ((2 * quad)     ^ (n & 7))];
      f32x4 c1 = Bs[buf][n * 8 + ((2 * quad + 1) ^ (n & 7))];
      bf16x8 b;
      b[0] = (__bf16)c0[0]; b[1] = (__bf16)c0[1];
      b[2] = (__bf16)c0[2]; b[3] = (__bf16)c0[3];
      b[4] = (__bf16)c1[0]; b[5] = (__bf16)c1[1];
      b[6] = (__bf16)c1[2]; b[7] = (__bf16)c1[3];
      bf[ni] = b;
    }
#pragma unroll
    for (int mi = 0; mi < 4; ++mi)
#pragma unroll
      for (int ni = 0; ni < 4; ++ni)
        acc[mi][ni] = __builtin_amdgcn_mfma_f32_16x16x32_bf16(
            af[mi], bf[ni], acc[mi][ni], 0, 0, 0);

    asm volatile("" ::: "memory");
    __builtin_amdgcn_s_barrier();   // reads of As/Bs[buf] done pre-overwrite
  }

  // Epilogue: C/D layout col=lane&15, row=quad*4+reg (verified m89/m91).
#pragma unroll
  for (int mi = 0; mi < 4; ++mi) {
    const int mb = wm + mi * 16 + quad * 4;
    const int t0 = rowtok_s[mb + 0];
    const int t1 = rowtok_s[mb + 1];
    const int t2 = rowtok_s[mb + 2];
    const int t3 = rowtok_s[mb + 3];
#pragma unroll
    for (int ni = 0; ni < 4; ++ni) {
      const int n = n0 + wn + ni * 16 + lr;
      f32x4 c = acc[mi][ni];
      if (t0 >= 0) out[(size_t)t0 * OUT_FEAT + n] = c[0];
      if (t1 >= 0) out[(size_t)t1 * OUT_FEAT + n] = c[1];
      if (t2 >= 0) out[(size_t)t2 * OUT_FEAT + n] = c[2];
      if (t3 >= 0) out[(size_t)t3 * OUT_FEAT + n] = c[3];
    }
  }
}

// ---------------------------------------------------------------------------
extern "C" void kernel_launch(void* const* d_in, const int* in_sizes, int n_in,
                              void* d_out, int out_size, void* d_ws, size_t ws_size,
                              hipStream_t stream) {
  const float* x    = (const float*)d_in[0];
  const int*   gate = (const int*)d_in[1];
  const float* w    = (const float*)d_in[2];
  float* out = (float*)d_out;

  // workspace layout (~8.1 MB)
  char* ws = (char*)d_ws;
  unsigned short* xs = (unsigned short*)ws;                        // 8 MB dense
  int* row_token = (int*)(ws + 8388608);                           // 32 KB
  int* pstart = row_token + MAX_ROWS;
  int* tile_e = pstart + NUM_EXPERT;
  int* tile_m = tile_e + MAX_TILES;

  k_setup<<<1, 256, 0, stream>>>(gate, pstart, tile_e, tile_m, row_token);
  k_cast<<<N_TOKENS * IN_FEAT / (8 * 256), 256, 0, stream>>>(
      (const float4*)x, (us8*)xs);
  dim3 g(OUT_FEAT / BN, MAX_TILES);   // (16, 32); empty slots early-exit
  k_gemm<<<g, 512, 0, stream>>>(xs, w, pstart, tile_e, tile_m, row_token, out);
}

// Round 8
// 253.685 us; speedup vs baseline: 1.1035x; 1.0441x over previous
//
#include <hip/hip_runtime.h>
#include <hip/hip_bf16.h>
#include <stdint.h>

// Problem constants (from reference)
#define N_TOKENS   4096
#define IN_FEAT    1024
#define OUT_FEAT   2048
#define NUM_EXPERT 16

// Primary GEMM tiling (m97-isomorphic): 128x128 tile, BK=32, 256 thr/4 waves.
#define BM 128
#define BN 128
#define BK 32
#define NT (IN_FEAT / BK)     // 32 K-steps
#define MAX_TILES 48          // quant=128: sum_e ceil(cnt_e/128) <= 47
#define MAX_ROWS  8192        // covers both padding quanta

#define XS_UNITS  (N_TOKENS * IN_FEAT / 8)            // 524288 us8 units
#define WB_UNITS  (NUM_EXPERT * OUT_FEAT * IN_FEAT / 8) // 4194304 us8 units

typedef __bf16 bf16x8 __attribute__((ext_vector_type(8)));
typedef float  f32x4  __attribute__((ext_vector_type(4)));
typedef unsigned short us8 __attribute__((ext_vector_type(8)));  // 16B

__device__ __forceinline__ unsigned short f32_to_bf16_rne(float f) {
  union { float f; uint32_t u; } v; v.f = f;
  uint32_t u = v.u;
  u += 0x7fffu + ((u >> 16) & 1u);   // round-nearest-even
  return (unsigned short)(u >> 16);
}

// async global->LDS, 16B per lane. LDS dest is wave-uniform base + lane*16;
// source address is PER-LANE.
__device__ __forceinline__ void async_copy16(const void* g, void* l) {
  __builtin_amdgcn_global_load_lds(
      (const __attribute__((address_space(1))) unsigned int*)g,
      (__attribute__((address_space(3))) unsigned int*)l, 16, 0, 0);
}

__device__ __forceinline__ us8 cast8(const float4 a, const float4 b) {
  us8 o;
  o[0] = f32_to_bf16_rne(a.x); o[1] = f32_to_bf16_rne(a.y);
  o[2] = f32_to_bf16_rne(a.z); o[3] = f32_to_bf16_rne(a.w);
  o[4] = f32_to_bf16_rne(b.x); o[5] = f32_to_bf16_rne(b.y);
  o[6] = f32_to_bf16_rne(b.z); o[7] = f32_to_bf16_rne(b.w);
  return o;
}

// ---------------------------------------------------------------------------
// Routing setup body (parameterized padding quantum). Single block, 256 thr.
// ---------------------------------------------------------------------------
__device__ __forceinline__ void setup_body(
    const int* __restrict__ gate, int* __restrict__ pstart,
    int* __restrict__ tile_e, int* __restrict__ tile_m,
    int* __restrict__ row_token, int qm, int max_tiles) {
  __shared__ int cnt[NUM_EXPERT];
  __shared__ int cur[NUM_EXPERT];
  __shared__ int ps[NUM_EXPERT];
  const int tid = threadIdx.x;
  if (tid < NUM_EXPERT) { cnt[tid] = 0; cur[tid] = 0; }
  __syncthreads();
  for (int b = tid; b < N_TOKENS; b += 256) atomicAdd(&cnt[gate[b]], 1);
  for (int r = tid; r < MAX_ROWS; r += 256) row_token[r] = -1;
  __syncthreads();
  if (tid == 0) {
    int p = 0, tot = 0;
    for (int e = 0; e < NUM_EXPERT; ++e) {
      ps[e] = p; pstart[e] = p;
      int nt = (cnt[e] + qm - 1) / qm;
      for (int t = 0; t < nt; ++t) { tile_e[tot] = e; tile_m[tot] = t; ++tot; }
      p += nt * qm;
    }
    for (int s = tot; s < max_tiles; ++s) { tile_e[s] = -1; tile_m[s] = 0; }
  }
  __syncthreads();
  for (int b = tid; b < N_TOKENS; b += 256) {
    int e = gate[b];
    int pos = atomicAdd(&cur[e], 1);
    row_token[ps[e] + pos] = b;
  }
}

// ---------------------------------------------------------------------------
// k_prep (primary path): block 0 = routing setup (quant=128); remaining
// blocks = dense bf16 casts of x (16 MB) and W (128 MB -> 64 MB). One
// kernel, fully parallel, ~216 MB of traffic (~32 us).
// ---------------------------------------------------------------------------
__global__ void k_prep(const float4* __restrict__ x,
                       const float4* __restrict__ w4,
                       const int* __restrict__ gate,
                       us8* __restrict__ xs, us8* __restrict__ wb,
                       int* __restrict__ pstart, int* __restrict__ tile_e,
                       int* __restrict__ tile_m, int* __restrict__ row_token) {
  const int b = blockIdx.x;
  if (b == 0) {
    setup_body(gate, pstart, tile_e, tile_m, row_token, BM, MAX_TILES);
    return;
  }
  const int i = (b - 1) * 256 + threadIdx.x;      // us8 unit index
  if (i < XS_UNITS) {
    xs[i] = cast8(x[i * 2], x[i * 2 + 1]);
  } else {
    const int j = i - XS_UNITS;                   // < WB_UNITS by grid sizing
    wb[j] = cast8(w4[j * 2], w4[j * 2 + 1]);
  }
}

// ---------------------------------------------------------------------------
// k_gemm (primary): grouped GEMM, BOTH OPERANDS bf16 -- instruction-for-
// instruction isomorphic to the measured-874-TF m97 structure: per thread
// per K-step 4 DMA + 8 ds_read_b128 + 16 MFMA, 16 KB staged, ZERO converts.
// A and B use the same verified staging/swizzle: slot(r,c) = r*4 +
// (c ^ ((r>>1)&3)), c = 16B chunk 0..3; source chunk cA=(tid&3)^((tid>>3)&3)
// makes the linear-dest DMA realize it (R0-verified self-consistency).
// A-DMA sources row_token-indexed into dense xs (R7-verified; pads->row 0,
// stores guarded). Double-buffered, counted vmcnt, raw barriers.
// ---------------------------------------------------------------------------
__global__ void __launch_bounds__(256)
k_gemm(const unsigned short* __restrict__ xs,   // [N_TOKENS][IN_FEAT] bf16
       const unsigned short* __restrict__ wb,   // [E][OUT_FEAT][IN_FEAT] bf16
       const int* __restrict__ pstart,
       const int* __restrict__ tile_e,
       const int* __restrict__ tile_m,
       const int* __restrict__ row_token,
       float* __restrict__ out) {
  __shared__ us8 As[2][512];    // 2 x 8 KB
  __shared__ us8 Bs[2][512];    // 2 x 8 KB
  __shared__ int rowtok_s[BM];

  const int slot = blockIdx.y;
  const int e = tile_e[slot];
  if (e < 0) return;
  const int seg0 = pstart[e] + tile_m[slot] * BM;
  const int n0 = blockIdx.x * BN;

  const int tid  = threadIdx.x;
  const int wid  = tid >> 6;
  const int lane = tid & 63;
  const int lr   = lane & 15;
  const int quad = lane >> 4;
  const int wm   = (wid >> 1) * 64;   // wave m-offset in tile
  const int wn   = (wid & 1) * 64;    // wave n-offset in tile

  if (tid < BM) rowtok_s[tid] = row_token[seg0 + tid];

  // Staging sources: 4 lanes per row (16B chunks), swizzled chunk formula.
  const int cA = (tid & 3) ^ ((tid >> 3) & 3);
  const int rt0 = row_token[seg0 + (tid >> 2)];
  const int rt1 = row_token[seg0 + 64 + (tid >> 2)];
  const unsigned short* agp0 =
      xs + (size_t)(rt0 < 0 ? 0 : rt0) * IN_FEAT + cA * 8;
  const unsigned short* agp1 =
      xs + (size_t)(rt1 < 0 ? 0 : rt1) * IN_FEAT + cA * 8;
  const unsigned short* bgp =
      wb + (size_t)e * OUT_FEAT * IN_FEAT
         + (size_t)(n0 + (tid >> 2)) * IN_FEAT + cA * 8;

  f32x4 acc[4][4];
  const f32x4 z = {0.f, 0.f, 0.f, 0.f};
#pragma unroll
  for (int i = 0; i < 4; ++i)
#pragma unroll
    for (int j = 0; j < 4; ++j) acc[i][j] = z;

  // 4 async DMA per thread per stage: A rows 0-63 / 64-127, B rows 0-63 /
  // 64-127. 16 KB total per step (m97 economics).
  auto stage = [&](int t, int b) {
    const int k0 = t * BK;
    async_copy16(agp0 + k0,                As[b] +       wid * 64);
    async_copy16(agp1 + k0,                As[b] + 256 + wid * 64);
    async_copy16(bgp  + k0,                Bs[b] +       wid * 64);
    async_copy16(bgp  + 64 * IN_FEAT + k0, Bs[b] + 256 + wid * 64);
  };

  stage(0, 0);   // prologue: 4 DMA in flight

  // Publish rowtok_s (raw s_barrier does not drain lgkmcnt).
  asm volatile("s_waitcnt lgkmcnt(0)" ::: "memory");
  __builtin_amdgcn_s_barrier();

  for (int t = 0; t < NT; ++t) {
    const int buf = t & 1;
    if (t + 1 < NT) {
      stage(t + 1, buf ^ 1);  // 8 in flight: 4 old (stage t) + 4 new
      asm volatile("s_waitcnt vmcnt(4)" ::: "memory");  // stage t landed
    } else {
      asm volatile("s_waitcnt vmcnt(0)" ::: "memory");
    }
    __builtin_amdgcn_s_barrier();   // stage-t visible to all waves
    asm volatile("" ::: "memory");

    bf16x8 af[4], bf[4];
#pragma unroll
    for (int mi = 0; mi < 4; ++mi) {
      const int n = wm + mi * 16 + lr;
      af[mi] = *(const bf16x8*)&As[buf][n * 4 + (quad ^ ((n >> 1) & 3))];
    }
#pragma unroll
    for (int ni = 0; ni < 4; ++ni) {
      const int n = wn + ni * 16 + lr;
      bf[ni] = *(const bf16x8*)&Bs[buf][n * 4 + (quad ^ ((n >> 1) & 3))];
    }
#pragma unroll
    for (int mi = 0; mi < 4; ++mi)
#pragma unroll
      for (int ni = 0; ni < 4; ++ni)
        acc[mi][ni] = __builtin_amdgcn_mfma_f32_16x16x32_bf16(
            af[mi], bf[ni], acc[mi][ni], 0, 0, 0);

    asm volatile("" ::: "memory");
    __builtin_amdgcn_s_barrier();   // reads of As/Bs[buf] done pre-overwrite
  }

  // Epilogue: C/D layout col=lane&15, row=quad*4+reg (verified m89/m91).
#pragma unroll
  for (int mi = 0; mi < 4; ++mi) {
    const int mb = wm + mi * 16 + quad * 4;
    const int t0 = rowtok_s[mb + 0];
    const int t1 = rowtok_s[mb + 1];
    const int t2 = rowtok_s[mb + 2];
    const int t3 = rowtok_s[mb + 3];
#pragma unroll
    for (int ni = 0; ni < 4; ++ni) {
      const int n = n0 + wn + ni * 16 + lr;
      f32x4 c = acc[mi][ni];
      if (t0 >= 0) out[(size_t)t0 * OUT_FEAT + n] = c[0];
      if (t1 >= 0) out[(size_t)t1 * OUT_FEAT + n] = c[1];
      if (t2 >= 0) out[(size_t)t2 * OUT_FEAT + n] = c[2];
      if (t3 >= 0) out[(size_t)t3 * OUT_FEAT + n] = c[3];
    }
  }
}

// ===========================================================================
// FALLBACK PATH (workspace too small for the 64 MB bf16 W buffer):
// R7 pipeline verbatim (measured 264.9 us total). quant=256 setup + dense
// x-cast + fp32-B 256x128 gemm.
// ===========================================================================
__global__ void k_cast_v7(const float4* __restrict__ x, us8* __restrict__ xs) {
  const int i = blockIdx.x * 256 + threadIdx.x;
  xs[i] = cast8(x[i * 2], x[i * 2 + 1]);
}

__global__ void k_setup_v7(const int* __restrict__ gate, int* __restrict__ pstart,
                           int* __restrict__ tile_e, int* __restrict__ tile_m,
                           int* __restrict__ row_token) {
  setup_body(gate, pstart, tile_e, tile_m, row_token, 256, 32);
}

__global__ void __launch_bounds__(512, 4)
k_gemm_v7(const unsigned short* __restrict__ xs,
          const float* __restrict__ w,
          const int* __restrict__ pstart,
          const int* __restrict__ tile_e,
          const int* __restrict__ tile_m,
          const int* __restrict__ row_token,
          float* __restrict__ out) {
  __shared__ us8   As[2][1024];
  __shared__ f32x4 Bs[2][1024];
  __shared__ int rowtok_s[256];

  const int slot = blockIdx.y;
  const int e = tile_e[slot];
  if (e < 0) return;
  const int seg0 = pstart[e] + tile_m[slot] * 256;
  const int n0 = blockIdx.x * 128;

  const int tid  = threadIdx.x;
  const int wid  = tid >> 6;
  const int lane = tid & 63;
  const int lr   = lane & 15;
  const int quad = lane >> 4;
  const int wm   = (wid >> 1) * 64;
  const int wn   = (wid & 1) * 64;

  if (tid < 256) rowtok_s[tid] = row_token[seg0 + tid];

  const int cA = (tid & 3) ^ ((tid >> 3) & 3);
  const int rt0 = row_token[seg0 + (tid >> 2)];
  const int rt1 = row_token[seg0 + 128 + (tid >> 2)];
  const unsigned short* agp0 = xs + (size_t)(rt0 < 0 ? 0 : rt0) * IN_FEAT + cA * 8;
  const unsigned short* agp1 = xs + (size_t)(rt1 < 0 ? 0 : rt1) * IN_FEAT + cA * 8;
  const int cB = (tid & 7) ^ ((tid >> 3) & 7);
  const float* bgp = w + (size_t)e * OUT_FEAT * IN_FEAT
                       + (size_t)(n0 + (tid >> 3)) * IN_FEAT + cB * 4;

  f32x4 acc[4][4];
  const f32x4 z = {0.f, 0.f, 0.f, 0.f};
#pragma unroll
  for (int i = 0; i < 4; ++i)
#pragma unroll
    for (int j = 0; j < 4; ++j) acc[i][j] = z;

  auto stage = [&](int t, int b) {
    const int k0 = t * BK;
    async_copy16(agp0 + k0,                As[b] +       wid * 64);
    async_copy16(agp1 + k0,                As[b] + 512 + wid * 64);
    async_copy16(bgp + k0,                 Bs[b] +       wid * 64);
    async_copy16(bgp + 64 * IN_FEAT + k0,  Bs[b] + 512 + wid * 64);
  };

  stage(0, 0);
  asm volatile("s_waitcnt lgkmcnt(0)" ::: "memory");
  __builtin_amdgcn_s_barrier();

  for (int t = 0; t < NT; ++t) {
    const int buf = t & 1;
    if (t + 1 < NT) {
      stage(t + 1, buf ^ 1);
      asm volatile("s_waitcnt vmcnt(4)" ::: "memory");
    } else {
      asm volatile("s_waitcnt vmcnt(0)" ::: "memory");
    }
    __builtin_amdgcn_s_barrier();
    asm volatile("" ::: "memory");

    bf16x8 af[4], bf[4];
#pragma unroll
    for (int mi = 0; mi < 4; ++mi) {
      const int n = wm + mi * 16 + lr;
      af[mi] = *(const bf16x8*)&As[buf][n * 4 + (quad ^ ((n >> 1) & 3))];
    }
#pragma unroll
    for (int ni = 0; ni < 4; ++ni) {
      const int n = wn + ni * 16 + lr;
      f32x4 c0 = Bs[buf][n * 8 + ((2 * quad)     ^ (n & 7))];
      f32x4 c1 = Bs[buf][n * 8 + ((2 * quad + 1) ^ (n & 7))];
      bf16x8 b;
      b[0] = (__bf16)c0[0]; b[1] = (__bf16)c0[1];
      b[2] = (__bf16)c0[2]; b[3] = (__bf16)c0[3];
      b[4] = (__bf16)c1[0]; b[5] = (__bf16)c1[1];
      b[6] = (__bf16)c1[2]; b[7] = (__bf16)c1[3];
      bf[ni] = b;
    }
#pragma unroll
    for (int mi = 0; mi < 4; ++mi)
#pragma unroll
      for (int ni = 0; ni < 4; ++ni)
        acc[mi][ni] = __builtin_amdgcn_mfma_f32_16x16x32_bf16(
            af[mi], bf[ni], acc[mi][ni], 0, 0, 0);

    asm volatile("" ::: "memory");
    __builtin_amdgcn_s_barrier();
  }

#pragma unroll
  for (int mi = 0; mi < 4; ++mi) {
    const int mb = wm + mi * 16 + quad * 4;
    const int t0 = rowtok_s[mb + 0];
    const int t1 = rowtok_s[mb + 1];
    const int t2 = rowtok_s[mb + 2];
    const int t3 = rowtok_s[mb + 3];
#pragma unroll
    for (int ni = 0; ni < 4; ++ni) {
      const int n = n0 + wn + ni * 16 + lr;
      f32x4 c = acc[mi][ni];
      if (t0 >= 0) out[(size_t)t0 * OUT_FEAT + n] = c[0];
      if (t1 >= 0) out[(size_t)t1 * OUT_FEAT + n] = c[1];
      if (t2 >= 0) out[(size_t)t2 * OUT_FEAT + n] = c[2];
      if (t3 >= 0) out[(size_t)t3 * OUT_FEAT + n] = c[3];
    }
  }
}

// ---------------------------------------------------------------------------
extern "C" void kernel_launch(void* const* d_in, const int* in_sizes, int n_in,
                              void* d_out, int out_size, void* d_ws, size_t ws_size,
                              hipStream_t stream) {
  const float* x    = (const float*)d_in[0];
  const int*   gate = (const int*)d_in[1];
  const float* w    = (const float*)d_in[2];
  float* out = (float*)d_out;
  char* ws = (char*)d_ws;

  const size_t XS_B = 8u * 1024 * 1024;    // xs bf16 (dense)
  const size_t WB_B = 64u * 1024 * 1024;   // wb bf16
  const size_t need = XS_B + WB_B + 64 * 1024;

  if (ws_size >= need) {
    // Primary path: pre-cast W to bf16, m97-isomorphic bf16 GEMM.
    unsigned short* xs = (unsigned short*)ws;
    unsigned short* wb = (unsigned short*)(ws + XS_B);
    int* row_token = (int*)(ws + XS_B + WB_B);              // 8192 ints
    int* pstart = row_token + MAX_ROWS;
    int* tile_e = pstart + NUM_EXPERT;
    int* tile_m = tile_e + MAX_TILES;

    k_prep<<<1 + (XS_UNITS + WB_UNITS) / 256, 256, 0, stream>>>(
        (const float4*)x, (const float4*)w, gate,
        (us8*)xs, (us8*)wb, pstart, tile_e, tile_m, row_token);
    dim3 g(OUT_FEAT / BN, MAX_TILES);   // (16, 48); empty slots early-exit
    k_gemm<<<g, 256, 0, stream>>>(xs, wb, pstart, tile_e, tile_m, row_token,
                                  out);
  } else {
    // Fallback: R7 pipeline verbatim.
    unsigned short* xs = (unsigned short*)ws;
    int* row_token = (int*)(ws + XS_B);
    int* pstart = row_token + MAX_ROWS;
    int* tile_e = pstart + NUM_EXPERT;
    int* tile_m = tile_e + 32;

    k_setup_v7<<<1, 256, 0, stream>>>(gate, pstart, tile_e, tile_m, row_token);
    k_cast_v7<<<XS_UNITS / 256, 256, 0, stream>>>((const float4*)x, (us8*)xs);
    dim3 g(OUT_FEAT / 128, 32);
    k_gemm_v7<<<g, 512, 0, stream>>>(xs, w, pstart, tile_e, tile_m, row_token,
                                     out);
  }
}